// Round 1
// baseline (209.387 us; speedup 1.0000x reference)
//
#include <hip/hip_runtime.h>
#include <math.h>

// Problem constants (from reference)
#define NPTS   131072
#define DIMC   256      // 16*16 output channels per point
#define YD     9
#define NPATHS 96
#define NPATH0 32
#define HID    64
#define NREG   65       // <= HID+1 relu-sign regions over t in [0,inf)
#define QSTR   18       // coeffs per (region, c): 9 for t*Y, 9 for Y

// ws layout (floats):
//   Q    : [NREG][DIMC][QSTR]              = 299520
//   xflip: [HID]                           (region knots, +inf if none)
//   k2   : [DIMC]                          (masked-out fallback)
// total ~1.2 MB

// ---------------------------------------------------------------------------
// Kernel A: per-region coefficient precompute. One block per region j.
//   sigma_h(region j) = base_h XOR (rank_h < j), rank = stable rank of knot.
//   v_j[w] = sum_h sigma a_h W2[h,w];  c_j[w] = sum_h sigma b_h W2[h,w] + b2[w]
//   Q[j][c][y]   = sum_w M1[c,y,w] * v_j[w]      (coefficient of t*Y_y)
//   Q[j][c][9+y] = sum_w M1[c,y,w] * c_j[w]      (coefficient of Y_y)
// ---------------------------------------------------------------------------
__global__ __launch_bounds__(256) void precompute_kernel(
    const float* __restrict__ W1, const float* __restrict__ b1,
    const float* __restrict__ W2, const float* __restrict__ b2,
    const float* __restrict__ M1, const float* __restrict__ M2,
    const float* __restrict__ wgt,
    float* __restrict__ Q, float* __restrict__ xout, float* __restrict__ k2out)
{
    const int j   = blockIdx.x;
    const int tid = threadIdx.x;
    __shared__ __align__(16) float sx[HID];
    __shared__ __align__(16) float sa[HID], sb[HID];
    __shared__ __align__(16) float ssa[HID], ssb[HID];
    __shared__ __align__(16) float sv[NPATHS], sc[NPATHS];

    if (tid < HID) {
        float a = W1[tid], b = b1[tid];
        sa[tid] = a; sb[tid] = b;
        // knot in (0,inf) exists iff a,b have opposite (strict) signs
        bool flips = (a > 0.f && b < 0.f) || (a < 0.f && b > 0.f);
        sx[tid] = flips ? (-b / a) : __builtin_inff();
    }
    __syncthreads();
    if (tid < HID) {
        float a = sa[tid], b = sb[tid], xh = sx[tid];
        int rank = 0;
        for (int k = 0; k < HID; ++k) {
            float xk = sx[k];
            rank += (xk < xh || (xk == xh && k < tid)) ? 1 : 0;
        }
        bool base = (b > 0.f) || (b == 0.f && a > 0.f);  // pattern at t->0+
        bool sig  = base ^ (rank < j);
        ssa[tid] = sig ? a : 0.f;
        ssb[tid] = sig ? b : 0.f;
    }
    __syncthreads();
    if (tid < NPATHS) {
        float vv = 0.f, cc = 0.f;
        for (int h = 0; h < HID; ++h) {
            float w2 = W2[h * NPATHS + tid];
            vv += ssa[h] * w2;
            cc += ssb[h] * w2;
        }
        sv[tid] = vv;
        sc[tid] = cc + b2[tid];
    }
    __syncthreads();
    {   // thread = output channel c; w-outer loop so sv/sc LDS reads amortize over y
        const int c = tid;
        float accP[YD], accD[YD];
        #pragma unroll
        for (int y = 0; y < YD; ++y) { accP[y] = 0.f; accD[y] = 0.f; }
        for (int w4 = 0; w4 < NPATHS / 4; ++w4) {
            float4 v4 = ((const float4*)sv)[w4];
            float4 c4 = ((const float4*)sc)[w4];
            #pragma unroll
            for (int y = 0; y < YD; ++y) {
                const float4 m4 = *(const float4*)(M1 + (size_t)(c * YD + y) * NPATHS + w4 * 4);
                accP[y] += m4.x * v4.x + m4.y * v4.y + m4.z * v4.z + m4.w * v4.w;
                accD[y] += m4.x * c4.x + m4.y * c4.y + m4.z * c4.z + m4.w * c4.w;
            }
        }
        float* qrow = Q + ((size_t)j * DIMC + c) * QSTR;
        #pragma unroll
        for (int y = 0; y < YD; ++y) {
            qrow[y]     = accP[y];
            qrow[9 + y] = accD[y];
        }
    }
    if (j == 0) {
        if (tid < HID) xout[tid] = sx[tid];
        float s = 0.f;
        #pragma unroll
        for (int k = 0; k < NPATH0; ++k) s += M2[tid * NPATH0 + k] * wgt[k];
        k2out[tid] = s;
    }
}

// ---------------------------------------------------------------------------
// Kernel B: main. Block = 256 threads, 64 points.
// Phase 1 (tid<64): t, Y, region id jj, mask -> 20-float LDS line per point.
// Phase 2: thread=(cg,pg), cg in [0,64) handles c-quad cg*4, pg splits the
// 64 points into 4 chunks of 16. Coef regs (72) reloaded only when jj changes
// (wave-uniform; once per block in practice).
// ---------------------------------------------------------------------------
__global__ __launch_bounds__(256) void main_kernel(
    const float* __restrict__ r, const float* __restrict__ Q,
    const float* __restrict__ xflip, const float* __restrict__ k2,
    float* __restrict__ out)
{
    __shared__ __align__(16) float qArr[64 * 20];
    const int tid = threadIdx.x;
    const int n0  = blockIdx.x * 64;

    if (tid < 64) {
        const int n = n0 + tid;
        float rx = r[(size_t)n * 3 + 0];
        float ry = r[(size_t)n * 3 + 1];
        float rz = r[(size_t)n * 3 + 2];
        float t  = sqrtf(rx * rx + ry * ry + rz * rz);
        float rcp = 1.f / fmaxf(t, 1e-12f);
        float ux = rx * rcp, uy = ry * rcp, uz = rz * rcp;
        const float c0 = 0.28209479177387814f;
        const float c1 = 0.4886025119029199f;
        const float c2 = 1.0925484305920792f;
        float Y[9];
        Y[0] = c0;
        Y[1] = c1 * uy;
        Y[2] = c1 * uz;
        Y[3] = c1 * ux;
        Y[4] = c2 * ux * uy;
        Y[5] = c2 * uy * uz;
        Y[6] = 0.31539156525252005f * (3.f * uz * uz - 1.f);
        Y[7] = c2 * ux * uz;
        Y[8] = 0.5462742152960396f * (ux * ux - uy * uy);
        int jj = 0;
        for (int h = 0; h < HID; ++h) jj += (xflip[h] < t) ? 1 : 0;
        float* q = qArr + tid * 20;
        #pragma unroll
        for (int y = 0; y < 9; ++y) { q[y] = t * Y[y]; q[9 + y] = Y[y]; }
        q[18] = (float)jj;
        q[19] = (t > 0.f) ? 1.f : 0.f;
    }
    __syncthreads();

    const int cg  = tid & 63;
    const int pg  = tid >> 6;
    const int c0i = cg * 4;
    const float4 k2v = *(const float4*)(k2 + c0i);

    float cfs[72];
    int curj = -1;
    const int pbeg = pg * 16;
    for (int p = pbeg; p < pbeg + 16; ++p) {
        const float4* qv = (const float4*)(qArr + p * 20);
        float4 a0 = qv[0], a1 = qv[1], a2 = qv[2], a3 = qv[3], a4 = qv[4];
        int jj = (int)a4.z;
        if (jj != curj) {               // wave-uniform (p identical in-wave)
            curj = jj;
            const float4* cb = (const float4*)(Q + ((size_t)jj * DIMC + c0i) * QSTR);
            #pragma unroll
            for (int v = 0; v < 18; ++v) {
                float4 t4 = cb[v];
                cfs[v * 4 + 0] = t4.x; cfs[v * 4 + 1] = t4.y;
                cfs[v * 4 + 2] = t4.z; cfs[v * 4 + 3] = t4.w;
            }
        }
        float qs[18] = { a0.x, a0.y, a0.z, a0.w,  a1.x, a1.y, a1.z, a1.w,
                         a2.x, a2.y, a2.z, a2.w,  a3.x, a3.y, a3.z, a3.w,
                         a4.x, a4.y };
        float acc0 = 0.f, acc1 = 0.f, acc2 = 0.f, acc3 = 0.f;
        #pragma unroll
        for (int i = 0; i < 18; ++i) {
            acc0 += qs[i] * cfs[0 * 18 + i];
            acc1 += qs[i] * cfs[1 * 18 + i];
            acc2 += qs[i] * cfs[2 * 18 + i];
            acc3 += qs[i] * cfs[3 * 18 + i];
        }
        const bool msk = (a4.w != 0.f);
        float4 o;
        o.x = msk ? acc0 : k2v.x;
        o.y = msk ? acc1 : k2v.y;
        o.z = msk ? acc2 : k2v.z;
        o.w = msk ? acc3 : k2v.w;
        *(float4*)(out + (size_t)(n0 + p) * DIMC + c0i) = o;
    }
}

extern "C" void kernel_launch(void* const* d_in, const int* in_sizes, int n_in,
                              void* d_out, int out_size, void* d_ws, size_t ws_size,
                              hipStream_t stream)
{
    const float* r   = (const float*)d_in[0];
    const float* M1  = (const float*)d_in[1];
    const float* M2  = (const float*)d_in[2];
    const float* wgt = (const float*)d_in[3];
    const float* W1  = (const float*)d_in[4];
    const float* b1  = (const float*)d_in[5];
    const float* W2  = (const float*)d_in[6];
    const float* b2  = (const float*)d_in[7];
    float* out = (float*)d_out;

    float* ws = (float*)d_ws;
    float* Q  = ws;
    float* xf = ws + (size_t)NREG * DIMC * QSTR;
    float* k2 = xf + HID;

    precompute_kernel<<<NREG, 256, 0, stream>>>(W1, b1, W2, b2, M1, M2, wgt, Q, xf, k2);
    main_kernel<<<NPTS / 64, 256, 0, stream>>>(r, Q, xf, k2, out);
}

// Round 3
// 200.053 us; speedup vs baseline: 1.0467x; 1.0467x over previous
//
#include <hip/hip_runtime.h>
#include <math.h>

// Problem constants (from reference)
#define NPTS   131072
#define DIMC   256      // 16*16 output channels per point
#define YD     9
#define NPATHS 96
#define NPATH0 32
#define HID    64
#define NREG   65       // <= HID+1 relu-sign regions over t in [0,inf)
#define QSTR   18       // coeffs per (region, c): 9 for t*Y, 9 for Y

typedef float f32x4 __attribute__((ext_vector_type(4)));

// ws layout (floats):
//   Q    : [NREG][DIMC][QSTR]              = 299520
//   xflip: [HID]                           (region knots, +inf if none)
//   k2   : [DIMC]                          (masked-out fallback)

// ---------------------------------------------------------------------------
// Kernel A: per-region coefficient precompute. One block per region j.
//   sigma_h(region j) = base_h XOR (rank_h < j), rank = stable rank of knot.
//   v_j[w] = sum_h sigma a_h W2[h,w];  c_j[w] = sum_h sigma b_h W2[h,w] + b2[w]
//   Q[j][c][y]   = sum_w M1[c,y,w] * v_j[w]      (coefficient of t*Y_y)
//   Q[j][c][9+y] = sum_w M1[c,y,w] * c_j[w]      (coefficient of Y_y)
// ---------------------------------------------------------------------------
__global__ __launch_bounds__(256) void precompute_kernel(
    const float* __restrict__ W1, const float* __restrict__ b1,
    const float* __restrict__ W2, const float* __restrict__ b2,
    const float* __restrict__ M1, const float* __restrict__ M2,
    const float* __restrict__ wgt,
    float* __restrict__ Q, float* __restrict__ xout, float* __restrict__ k2out)
{
    const int j   = blockIdx.x;
    const int tid = threadIdx.x;
    __shared__ __align__(16) float sx[HID];
    __shared__ __align__(16) float sa[HID], sb[HID];
    __shared__ __align__(16) float ssa[HID], ssb[HID];
    __shared__ __align__(16) float sv[NPATHS], sc[NPATHS];

    if (tid < HID) {
        float a = W1[tid], b = b1[tid];
        sa[tid] = a; sb[tid] = b;
        // knot in (0,inf) exists iff a,b have opposite (strict) signs
        bool flips = (a > 0.f && b < 0.f) || (a < 0.f && b > 0.f);
        sx[tid] = flips ? (-b / a) : __builtin_inff();
    }
    __syncthreads();
    if (tid < HID) {
        float a = sa[tid], b = sb[tid], xh = sx[tid];
        int rank = 0;
        for (int k = 0; k < HID; ++k) {
            float xk = sx[k];
            rank += (xk < xh || (xk == xh && k < tid)) ? 1 : 0;
        }
        bool base = (b > 0.f) || (b == 0.f && a > 0.f);  // pattern at t->0+
        bool sig  = base ^ (rank < j);
        ssa[tid] = sig ? a : 0.f;
        ssb[tid] = sig ? b : 0.f;
    }
    __syncthreads();
    if (tid < NPATHS) {
        float vv = 0.f, cc = 0.f;
        for (int h = 0; h < HID; ++h) {
            float w2 = W2[h * NPATHS + tid];
            vv += ssa[h] * w2;
            cc += ssb[h] * w2;
        }
        sv[tid] = vv;
        sc[tid] = cc + b2[tid];
    }
    __syncthreads();
    {   // thread = output channel c; w-outer loop so sv/sc LDS reads amortize over y
        const int c = tid;
        float accP[YD], accD[YD];
        #pragma unroll
        for (int y = 0; y < YD; ++y) { accP[y] = 0.f; accD[y] = 0.f; }
        for (int w4 = 0; w4 < NPATHS / 4; ++w4) {
            float4 v4 = ((const float4*)sv)[w4];
            float4 c4 = ((const float4*)sc)[w4];
            #pragma unroll
            for (int y = 0; y < YD; ++y) {
                const float4 m4 = *(const float4*)(M1 + (size_t)(c * YD + y) * NPATHS + w4 * 4);
                accP[y] += m4.x * v4.x + m4.y * v4.y + m4.z * v4.z + m4.w * v4.w;
                accD[y] += m4.x * c4.x + m4.y * c4.y + m4.z * c4.z + m4.w * c4.w;
            }
        }
        float* qrow = Q + ((size_t)j * DIMC + c) * QSTR;
        #pragma unroll
        for (int y = 0; y < YD; ++y) {
            qrow[y]     = accP[y];
            qrow[9 + y] = accD[y];
        }
    }
    if (j == 0) {
        if (tid < HID) xout[tid] = sx[tid];
        float s = 0.f;
        #pragma unroll
        for (int k = 0; k < NPATH0; ++k) s += M2[tid * NPATH0 + k] * wgt[k];
        k2out[tid] = s;
    }
}

// ---------------------------------------------------------------------------
// Kernel B: main. Block = 256 threads, 64 points.
// Phase 1 (tid<64 = wave 0): t, Y, region id jj, mask -> 20-float LDS line
// per point; ballot-detect whether all 64 points share one region.
// Phase 2: thread=(cg,pg), cg in [0,64) handles c-quad cg*4, pg splits the
// 64 points into 4 chunks of 16.
//   - uniform-region path (always, for this data): 72 coef floats loaded
//     unconditionally into registers ONCE, tight unrolled loop, nt stores.
//   - divergent fallback: per-point coefficient reload (wave-uniform branch).
// ---------------------------------------------------------------------------
__global__ __launch_bounds__(256) void main_kernel(
    const float* __restrict__ r, const float* __restrict__ Q,
    const float* __restrict__ xflip, const float* __restrict__ k2,
    float* __restrict__ out)
{
    __shared__ __align__(16) float qArr[64 * 20];
    __shared__ int sUni, sJJ0;
    const int tid = threadIdx.x;
    const int n0  = blockIdx.x * 64;

    if (tid < 64) {
        const int n = n0 + tid;
        float rx = r[(size_t)n * 3 + 0];
        float ry = r[(size_t)n * 3 + 1];
        float rz = r[(size_t)n * 3 + 2];
        float t  = sqrtf(rx * rx + ry * ry + rz * rz);
        float rcp = 1.f / fmaxf(t, 1e-12f);
        float ux = rx * rcp, uy = ry * rcp, uz = rz * rcp;
        const float c0 = 0.28209479177387814f;
        const float c1 = 0.4886025119029199f;
        const float c2 = 1.0925484305920792f;
        float Y[9];
        Y[0] = c0;
        Y[1] = c1 * uy;
        Y[2] = c1 * uz;
        Y[3] = c1 * ux;
        Y[4] = c2 * ux * uy;
        Y[5] = c2 * uy * uz;
        Y[6] = 0.31539156525252005f * (3.f * uz * uz - 1.f);
        Y[7] = c2 * ux * uz;
        Y[8] = 0.5462742152960396f * (ux * ux - uy * uy);
        int jj = 0;
        for (int h = 0; h < HID; ++h) jj += (xflip[h] < t) ? 1 : 0;
        float* q = qArr + tid * 20;
        #pragma unroll
        for (int y = 0; y < 9; ++y) { q[y] = t * Y[y]; q[9 + y] = Y[y]; }
        q[18] = (float)jj;
        q[19] = (t > 0.f) ? 1.f : 0.f;
        // wave 0 is fully active here: detect region-uniformity
        int jj0 = __shfl(jj, 0, 64);
        unsigned long long bal = __ballot(jj == jj0);
        if (tid == 0) { sUni = (bal == 0xFFFFFFFFFFFFFFFFULL) ? 1 : 0; sJJ0 = jj0; }
    }
    __syncthreads();

    const int cg  = tid & 63;
    const int pg  = tid >> 6;
    const int c0i = cg * 4;
    const float4 k2v = *(const float4*)(k2 + c0i);
    const int pbeg = pg * 16;

    if (sUni) {
        // ---- hot path: one region for the whole block ----
        const float4* cb = (const float4*)(Q + ((size_t)sJJ0 * DIMC + c0i) * QSTR);
        float cfs[72];
        #pragma unroll
        for (int v = 0; v < 18; ++v) {
            float4 t4 = cb[v];
            cfs[v * 4 + 0] = t4.x; cfs[v * 4 + 1] = t4.y;
            cfs[v * 4 + 2] = t4.z; cfs[v * 4 + 3] = t4.w;
        }
        #pragma unroll
        for (int p = pbeg; p < pbeg + 16; ++p) {
            const float4* qv = (const float4*)(qArr + p * 20);
            float4 a0 = qv[0], a1 = qv[1], a2 = qv[2], a3 = qv[3], a4 = qv[4];
            float qs[18] = { a0.x, a0.y, a0.z, a0.w,  a1.x, a1.y, a1.z, a1.w,
                             a2.x, a2.y, a2.z, a2.w,  a3.x, a3.y, a3.z, a3.w,
                             a4.x, a4.y };
            float acc0 = 0.f, acc1 = 0.f, acc2 = 0.f, acc3 = 0.f;
            #pragma unroll
            for (int i = 0; i < 18; ++i) {
                acc0 += qs[i] * cfs[0 * 18 + i];
                acc1 += qs[i] * cfs[1 * 18 + i];
                acc2 += qs[i] * cfs[2 * 18 + i];
                acc3 += qs[i] * cfs[3 * 18 + i];
            }
            const bool msk = (a4.w != 0.f);
            f32x4 o;
            o.x = msk ? acc0 : k2v.x;
            o.y = msk ? acc1 : k2v.y;
            o.z = msk ? acc2 : k2v.z;
            o.w = msk ? acc3 : k2v.w;
            __builtin_nontemporal_store(o, (f32x4*)(out + (size_t)(n0 + p) * DIMC + c0i));
        }
    } else {
        // ---- fallback: mixed regions in block (general correctness) ----
        float cfs[72];
        int curj = -1;
        for (int p = pbeg; p < pbeg + 16; ++p) {
            const float4* qv = (const float4*)(qArr + p * 20);
            float4 a0 = qv[0], a1 = qv[1], a2 = qv[2], a3 = qv[3], a4 = qv[4];
            int jj = (int)a4.z;
            if (jj != curj) {               // wave-uniform (p identical in-wave)
                curj = jj;
                const float4* cb = (const float4*)(Q + ((size_t)jj * DIMC + c0i) * QSTR);
                #pragma unroll
                for (int v = 0; v < 18; ++v) {
                    float4 t4 = cb[v];
                    cfs[v * 4 + 0] = t4.x; cfs[v * 4 + 1] = t4.y;
                    cfs[v * 4 + 2] = t4.z; cfs[v * 4 + 3] = t4.w;
                }
            }
            float qs[18] = { a0.x, a0.y, a0.z, a0.w,  a1.x, a1.y, a1.z, a1.w,
                             a2.x, a2.y, a2.z, a2.w,  a3.x, a3.y, a3.z, a3.w,
                             a4.x, a4.y };
            float acc0 = 0.f, acc1 = 0.f, acc2 = 0.f, acc3 = 0.f;
            #pragma unroll
            for (int i = 0; i < 18; ++i) {
                acc0 += qs[i] * cfs[0 * 18 + i];
                acc1 += qs[i] * cfs[1 * 18 + i];
                acc2 += qs[i] * cfs[2 * 18 + i];
                acc3 += qs[i] * cfs[3 * 18 + i];
            }
            const bool msk = (a4.w != 0.f);
            float4 o;
            o.x = msk ? acc0 : k2v.x;
            o.y = msk ? acc1 : k2v.y;
            o.z = msk ? acc2 : k2v.z;
            o.w = msk ? acc3 : k2v.w;
            *(float4*)(out + (size_t)(n0 + p) * DIMC + c0i) = o;
        }
    }
}

extern "C" void kernel_launch(void* const* d_in, const int* in_sizes, int n_in,
                              void* d_out, int out_size, void* d_ws, size_t ws_size,
                              hipStream_t stream)
{
    const float* r   = (const float*)d_in[0];
    const float* M1  = (const float*)d_in[1];
    const float* M2  = (const float*)d_in[2];
    const float* wgt = (const float*)d_in[3];
    const float* W1  = (const float*)d_in[4];
    const float* b1  = (const float*)d_in[5];
    const float* W2  = (const float*)d_in[6];
    const float* b2  = (const float*)d_in[7];
    float* out = (float*)d_out;

    float* ws = (float*)d_ws;
    float* Q  = ws;
    float* xf = ws + (size_t)NREG * DIMC * QSTR;
    float* k2 = xf + HID;

    precompute_kernel<<<NREG, 256, 0, stream>>>(W1, b1, W2, b2, M1, M2, wgt, Q, xf, k2);
    main_kernel<<<NPTS / 64, 256, 0, stream>>>(r, Q, xf, k2, out);
}